// Round 1
// baseline (1646.128 us; speedup 1.0000x reference)
//
#include <hip/hip_runtime.h>
#include <math.h>

#define N_NODES  50000
#define N_EDGES  800000
#define HIDDEN   128
#define N_GRAPHS 32
#define GN_EPS   1e-5f

// ---- workspace layout (float offsets) ----
#define DEG_OFF   0              // 50000 floats
#define GSUM_OFF  50048          // 32*128
#define GVAR_OFF  54144          // 32*128
#define GCNT_OFF  58240          // 32
#define WS_FLOATS 58272

// Scatter x[src] rows into msg (=d_out) with f32 atomics; count degree.
__global__ __launch_bounds__(256) void edge_scatter(const float* __restrict__ x,
    const int* __restrict__ ei, float* __restrict__ msg, float* __restrict__ deg) {
  int t = blockIdx.x * 256 + threadIdx.x;
  int e = t >> 5, q = t & 31;
  if (e >= N_EDGES) return;
  int src = ei[e];
  int dst = ei[N_EDGES + e];
  float4 v = *(const float4*)(x + (size_t)src * HIDDEN + q * 4);
  float* m = msg + (size_t)dst * HIDDEN + q * 4;
  atomicAdd(m + 0, v.x);
  atomicAdd(m + 1, v.y);
  atomicAdd(m + 2, v.z);
  atomicAdd(m + 3, v.w);
  if (q == 0) atomicAdd(deg + dst, 1.0f);
}

// out[n] = (msg[n]/max(deg,1)) @ W_l + b_l + x[n] @ W_r   (in place on msg==out==d_out)
__global__ __launch_bounds__(256) void linear_k(float* __restrict__ out,
    const float* __restrict__ deg, const float* __restrict__ x,
    const float* __restrict__ Wl, const float* __restrict__ bl,
    const float* __restrict__ Wr) {
  __shared__ float a_s[2][HIDDEN];
  __shared__ float x_s[2][HIDDEN];
  int tid = threadIdx.x;
  int ln = tid >> 7;     // node slot in block
  int d  = tid & 127;
  int n = blockIdx.x * 2 + ln;
  if (n < N_NODES) {
    float inv = 1.0f / fmaxf(deg[n], 1.0f);
    a_s[ln][d] = out[(size_t)n * HIDDEN + d] * inv;
    x_s[ln][d] = x[(size_t)n * HIDDEN + d];
  }
  __syncthreads();
  if (n >= N_NODES) return;
  float acc = bl[d];
#pragma unroll 8
  for (int k = 0; k < HIDDEN; ++k) {
    acc += a_s[ln][k] * Wl[k * HIDDEN + d] + x_s[ln][k] * Wr[k * HIDDEN + d];
  }
  out[(size_t)n * HIDDEN + d] = acc;
}

// histogram of batch -> per-graph node counts (float)
__global__ __launch_bounds__(256) void gcnt_hist(const int* __restrict__ batch,
                                                 float* __restrict__ gcnt) {
  __shared__ int h[N_GRAPHS];
  int tid = threadIdx.x;
  if (tid < N_GRAPHS) h[tid] = 0;
  __syncthreads();
  int n = blockIdx.x * 256 + tid;
  if (n < N_NODES) atomicAdd(&h[batch[n]], 1);
  __syncthreads();
  if (tid < N_GRAPHS && h[tid]) atomicAdd(gcnt + tid, (float)h[tid]);
}

// PASS 0: per-graph sum of out.  PASS 1: per-graph sum of (out - alpha*mean)^2.
// batch is sorted -> each block covers 64 contiguous nodes, flush on transition.
template <int PASS>
__global__ __launch_bounds__(128) void seg_reduce(const float* __restrict__ out,
    const int* __restrict__ batch, const float* __restrict__ mean,
    const float* __restrict__ alpha, float* __restrict__ dst) {
  int d = threadIdx.x;
  int nstart = blockIdx.x * 64;
  int nend = min(nstart + 64, N_NODES);
  if (nstart >= N_NODES) return;
  int cur = batch[nstart];
  float acc = 0.0f;
  float al = 0.0f, m = 0.0f;
  if (PASS == 1) { al = alpha[d]; m = mean[cur * HIDDEN + d]; }
  for (int n = nstart; n < nend; ++n) {
    int g = batch[n];
    if (g != cur) {
      atomicAdd(dst + cur * HIDDEN + d, acc);
      acc = 0.0f;
      cur = g;
      if (PASS == 1) m = mean[cur * HIDDEN + d];
    }
    float v = out[(size_t)n * HIDDEN + d];
    if (PASS == 1) { float s = v - al * m; v = s * s; }
    acc += v;
  }
  atomicAdd(dst + cur * HIDDEN + d, acc);
}

// gsum -> mean (in place)
__global__ __launch_bounds__(256) void mean_div(float* __restrict__ gsum,
                                                const float* __restrict__ gcnt) {
  int i = blockIdx.x * 256 + threadIdx.x;
  if (i >= N_GRAPHS * HIDDEN) return;
  gsum[i] = gsum[i] / fmaxf(gcnt[i >> 7], 1.0f);
}

// gvar -> 1/sqrt(var/cnt + eps) (in place)
__global__ __launch_bounds__(256) void rstd_k(float* __restrict__ gvar,
                                              const float* __restrict__ gcnt) {
  int i = blockIdx.x * 256 + threadIdx.x;
  if (i >= N_GRAPHS * HIDDEN) return;
  float var = gvar[i] / fmaxf(gcnt[i >> 7], 1.0f);
  gvar[i] = rsqrtf(var + GN_EPS);
}

// normed = gw*(out-alpha*mean)*rstd + gb; d_out = gelu_exact(normed) + x  (in place)
__global__ __launch_bounds__(256) void final_k(float* __restrict__ out,
    const float* __restrict__ x, const int* __restrict__ batch,
    const float* __restrict__ mean, const float* __restrict__ rstd,
    const float* __restrict__ alpha, const float* __restrict__ gw,
    const float* __restrict__ gb) {
  size_t i = ((size_t)blockIdx.x * 256 + threadIdx.x) * 4;
  if (i >= (size_t)N_NODES * HIDDEN) return;
  int n = (int)(i >> 7);
  int d = (int)(i & 127);
  int g = batch[n];
  float4 v  = *(float4*)(out + i);
  float4 xv = *(const float4*)(x + i);
  float4 al = *(const float4*)(alpha + d);
  float4 w  = *(const float4*)(gw + d);
  float4 b  = *(const float4*)(gb + d);
  float4 mn = *(const float4*)(mean + (size_t)g * HIDDEN + d);
  float4 rs = *(const float4*)(rstd + (size_t)g * HIDDEN + d);
  float r[4];
  float vv[4]  = {v.x, v.y, v.z, v.w};
  float xx[4]  = {xv.x, xv.y, xv.z, xv.w};
  float aa[4]  = {al.x, al.y, al.z, al.w};
  float ww[4]  = {w.x, w.y, w.z, w.w};
  float bb[4]  = {b.x, b.y, b.z, b.w};
  float mm[4]  = {mn.x, mn.y, mn.z, mn.w};
  float rr[4]  = {rs.x, rs.y, rs.z, rs.w};
#pragma unroll
  for (int c = 0; c < 4; ++c) {
    float sub = vv[c] - aa[c] * mm[c];
    float nm  = ww[c] * sub * rr[c] + bb[c];
    float ge  = 0.5f * nm * (1.0f + erff(nm * 0.70710678118654752f));
    r[c] = ge + xx[c];
  }
  float4 res = {r[0], r[1], r[2], r[3]};
  *(float4*)(out + i) = res;
}

extern "C" void kernel_launch(void* const* d_in, const int* in_sizes, int n_in,
                              void* d_out, int out_size, void* d_ws, size_t ws_size,
                              hipStream_t stream) {
  const float* x     = (const float*)d_in[0];
  const int*   ei    = (const int*)d_in[1];
  const int*   batch = (const int*)d_in[2];
  const float* Wl    = (const float*)d_in[3];
  const float* bl    = (const float*)d_in[4];
  const float* Wr    = (const float*)d_in[5];
  const float* gw    = (const float*)d_in[6];
  const float* gb    = (const float*)d_in[7];
  const float* alpha = (const float*)d_in[8];

  float* out = (float*)d_out;
  float* ws  = (float*)d_ws;
  float* deg  = ws + DEG_OFF;
  float* gsum = ws + GSUM_OFF;   // becomes mean
  float* gvar = ws + GVAR_OFF;   // becomes rstd
  float* gcnt = ws + GCNT_OFF;

  // zero msg accumulator (d_out) and ws stats
  hipMemsetAsync(d_out, 0, (size_t)N_NODES * HIDDEN * sizeof(float), stream);
  hipMemsetAsync(d_ws, 0, (size_t)WS_FLOATS * sizeof(float), stream);

  // 1) scatter-aggregate into d_out, count degree
  edge_scatter<<<(N_EDGES * 32) / 256, 256, 0, stream>>>(x, ei, out, deg);

  // 2) linear (in place on d_out)
  linear_k<<<N_NODES / 2, 256, 0, stream>>>(out, deg, x, Wl, bl, Wr);

  // 3) graph counts + mean
  gcnt_hist<<<(N_NODES + 255) / 256, 256, 0, stream>>>(batch, gcnt);
  seg_reduce<0><<<(N_NODES + 63) / 64, 128, 0, stream>>>(out, batch, nullptr, nullptr, gsum);
  mean_div<<<(N_GRAPHS * HIDDEN + 255) / 256, 256, 0, stream>>>(gsum, gcnt);

  // 4) variance -> rstd
  seg_reduce<1><<<(N_NODES + 63) / 64, 128, 0, stream>>>(out, batch, gsum, alpha, gvar);
  rstd_k<<<(N_GRAPHS * HIDDEN + 255) / 256, 256, 0, stream>>>(gvar, gcnt);

  // 5) normalize + GELU + residual (in place)
  final_k<<<(N_NODES * HIDDEN / 4 + 255) / 256, 256, 0, stream>>>(
      out, x, batch, gsum, gvar, alpha, gw, gb);
}

// Round 2
// 501.774 us; speedup vs baseline: 3.2806x; 3.2806x over previous
//
#include <hip/hip_runtime.h>
#include <math.h>

#define N_NODES  50000
#define N_EDGES  800000
#define HIDDEN   128
#define N_GRAPHS 32
#define GN_EPS   1e-5f

// ---- workspace layout (int offsets within ws viewed as int*/float*) ----
#define ROWPTR_OFF 0          // 50001 ints
#define CURSOR_OFF 50016      // 50016 ints (also used as count histogram)
#define SRCS_OFF   100032     // 800000 ints
#define GSUM_OFF   900048     // 4096 floats
#define GVAR_OFF   904144     // 4096 floats
#define GCNT_OFF   908240     // 32 floats
#define STATS_FLOATS (4096 + 4096 + 32)

// 1) histogram of destination degrees (int atomics)
__global__ __launch_bounds__(256) void hist_k(const int* __restrict__ ei,
                                              int* __restrict__ cnt) {
  int e = blockIdx.x * 256 + threadIdx.x;
  if (e >= N_EDGES) return;
  atomicAdd(&cnt[ei[N_EDGES + e]], 1);
}

// 2) single-block exclusive scan of counts -> rowptr, cursor copy
__global__ __launch_bounds__(1024) void scan_k(const int* __restrict__ cnt,
                                               int* __restrict__ rowptr,
                                               int* __restrict__ cursor) {
  __shared__ int ssum[1024];
  int tid = threadIdx.x;
  const int CH = (N_NODES + 1023) / 1024;  // 49
  int start = tid * CH;
  int end = min(start + CH, N_NODES);
  int s = 0;
  for (int i = start; i < end; ++i) s += cnt[i];
  ssum[tid] = s;
  __syncthreads();
  for (int off = 1; off < 1024; off <<= 1) {
    int v = (tid >= off) ? ssum[tid - off] : 0;
    __syncthreads();
    ssum[tid] += v;
    __syncthreads();
  }
  int run = (tid == 0) ? 0 : ssum[tid - 1];
  for (int i = start; i < end; ++i) {
    rowptr[i] = run;
    cursor[i] = run;
    run += cnt[i];
  }
  if (tid == 1023) rowptr[N_NODES] = ssum[1023];
}

// 3) counting sort: place src ids into dst-grouped order
__global__ __launch_bounds__(256) void sort_k(const int* __restrict__ ei,
                                              int* __restrict__ cursor,
                                              int* __restrict__ srcs) {
  int e = blockIdx.x * 256 + threadIdx.x;
  if (e >= N_EDGES) return;
  int src = ei[e];
  int dst = ei[N_EDGES + e];
  int pos = atomicAdd(&cursor[dst], 1);
  srcs[pos] = src;
}

// 4) gather + mean: out[n] = sum(x[srcs]) / max(deg,1)
__global__ __launch_bounds__(256) void gather_k(const float* __restrict__ x,
    const int* __restrict__ rowptr, const int* __restrict__ srcs,
    float* __restrict__ out) {
  int t = blockIdx.x * 256 + threadIdx.x;
  int n = t >> 5, q = t & 31;
  if (n >= N_NODES) return;
  int b = rowptr[n], e = rowptr[n + 1];
  float ax = 0.0f, ay = 0.0f, az = 0.0f, aw = 0.0f;
  for (int i = b; i < e; ++i) {
    int s = srcs[i];
    float4 v = *(const float4*)(x + (size_t)s * HIDDEN + q * 4);
    ax += v.x; ay += v.y; az += v.z; aw += v.w;
  }
  float inv = 1.0f / fmaxf((float)(e - b), 1.0f);
  float4 r = {ax * inv, ay * inv, az * inv, aw * inv};
  *(float4*)(out + (size_t)n * HIDDEN + q * 4) = r;
}

// out[n] = agg[n] @ W_l + b_l + x[n] @ W_r   (in place on agg==out==d_out)
__global__ __launch_bounds__(256) void linear_k(float* __restrict__ out,
    const float* __restrict__ x,
    const float* __restrict__ Wl, const float* __restrict__ bl,
    const float* __restrict__ Wr) {
  __shared__ float a_s[2][HIDDEN];
  __shared__ float x_s[2][HIDDEN];
  int tid = threadIdx.x;
  int ln = tid >> 7;
  int d  = tid & 127;
  int n = blockIdx.x * 2 + ln;
  if (n < N_NODES) {
    a_s[ln][d] = out[(size_t)n * HIDDEN + d];
    x_s[ln][d] = x[(size_t)n * HIDDEN + d];
  }
  __syncthreads();
  if (n >= N_NODES) return;
  float acc = bl[d];
#pragma unroll 8
  for (int k = 0; k < HIDDEN; ++k) {
    acc += a_s[ln][k] * Wl[k * HIDDEN + d] + x_s[ln][k] * Wr[k * HIDDEN + d];
  }
  out[(size_t)n * HIDDEN + d] = acc;
}

// histogram of batch -> per-graph node counts (float)
__global__ __launch_bounds__(256) void gcnt_hist(const int* __restrict__ batch,
                                                 float* __restrict__ gcnt) {
  __shared__ int h[N_GRAPHS];
  int tid = threadIdx.x;
  if (tid < N_GRAPHS) h[tid] = 0;
  __syncthreads();
  int n = blockIdx.x * 256 + tid;
  if (n < N_NODES) atomicAdd(&h[batch[n]], 1);
  __syncthreads();
  if (tid < N_GRAPHS && h[tid]) atomicAdd(gcnt + tid, (float)h[tid]);
}

// PASS 0: per-graph sum of out.  PASS 1: per-graph sum of (out - alpha*mean)^2.
template <int PASS>
__global__ __launch_bounds__(128) void seg_reduce(const float* __restrict__ out,
    const int* __restrict__ batch, const float* __restrict__ mean,
    const float* __restrict__ alpha, float* __restrict__ dst) {
  int d = threadIdx.x;
  int nstart = blockIdx.x * 64;
  int nend = min(nstart + 64, N_NODES);
  if (nstart >= N_NODES) return;
  int cur = batch[nstart];
  float acc = 0.0f;
  float al = 0.0f, m = 0.0f;
  if (PASS == 1) { al = alpha[d]; m = mean[cur * HIDDEN + d]; }
  for (int n = nstart; n < nend; ++n) {
    int g = batch[n];
    if (g != cur) {
      atomicAdd(dst + cur * HIDDEN + d, acc);
      acc = 0.0f;
      cur = g;
      if (PASS == 1) m = mean[cur * HIDDEN + d];
    }
    float v = out[(size_t)n * HIDDEN + d];
    if (PASS == 1) { float s = v - al * m; v = s * s; }
    acc += v;
  }
  atomicAdd(dst + cur * HIDDEN + d, acc);
}

__global__ __launch_bounds__(256) void mean_div(float* __restrict__ gsum,
                                                const float* __restrict__ gcnt) {
  int i = blockIdx.x * 256 + threadIdx.x;
  if (i >= N_GRAPHS * HIDDEN) return;
  gsum[i] = gsum[i] / fmaxf(gcnt[i >> 7], 1.0f);
}

__global__ __launch_bounds__(256) void rstd_k(float* __restrict__ gvar,
                                              const float* __restrict__ gcnt) {
  int i = blockIdx.x * 256 + threadIdx.x;
  if (i >= N_GRAPHS * HIDDEN) return;
  float var = gvar[i] / fmaxf(gcnt[i >> 7], 1.0f);
  gvar[i] = rsqrtf(var + GN_EPS);
}

// normed = gw*(out-alpha*mean)*rstd + gb; d_out = gelu_exact(normed) + x
__global__ __launch_bounds__(256) void final_k(float* __restrict__ out,
    const float* __restrict__ x, const int* __restrict__ batch,
    const float* __restrict__ mean, const float* __restrict__ rstd,
    const float* __restrict__ alpha, const float* __restrict__ gw,
    const float* __restrict__ gb) {
  size_t i = ((size_t)blockIdx.x * 256 + threadIdx.x) * 4;
  if (i >= (size_t)N_NODES * HIDDEN) return;
  int n = (int)(i >> 7);
  int d = (int)(i & 127);
  int g = batch[n];
  float4 v  = *(float4*)(out + i);
  float4 xv = *(const float4*)(x + i);
  float4 al = *(const float4*)(alpha + d);
  float4 w  = *(const float4*)(gw + d);
  float4 b  = *(const float4*)(gb + d);
  float4 mn = *(const float4*)(mean + (size_t)g * HIDDEN + d);
  float4 rs = *(const float4*)(rstd + (size_t)g * HIDDEN + d);
  float vv[4]  = {v.x, v.y, v.z, v.w};
  float xx[4]  = {xv.x, xv.y, xv.z, xv.w};
  float aa[4]  = {al.x, al.y, al.z, al.w};
  float ww[4]  = {w.x, w.y, w.z, w.w};
  float bb[4]  = {b.x, b.y, b.z, b.w};
  float mm[4]  = {mn.x, mn.y, mn.z, mn.w};
  float rr[4]  = {rs.x, rs.y, rs.z, rs.w};
  float r[4];
#pragma unroll
  for (int c = 0; c < 4; ++c) {
    float sub = vv[c] - aa[c] * mm[c];
    float nm  = ww[c] * sub * rr[c] + bb[c];
    float ge  = 0.5f * nm * (1.0f + erff(nm * 0.70710678118654752f));
    r[c] = ge + xx[c];
  }
  float4 res = {r[0], r[1], r[2], r[3]};
  *(float4*)(out + i) = res;
}

extern "C" void kernel_launch(void* const* d_in, const int* in_sizes, int n_in,
                              void* d_out, int out_size, void* d_ws, size_t ws_size,
                              hipStream_t stream) {
  const float* x     = (const float*)d_in[0];
  const int*   ei    = (const int*)d_in[1];
  const int*   batch = (const int*)d_in[2];
  const float* Wl    = (const float*)d_in[3];
  const float* bl    = (const float*)d_in[4];
  const float* Wr    = (const float*)d_in[5];
  const float* gw    = (const float*)d_in[6];
  const float* gb    = (const float*)d_in[7];
  const float* alpha = (const float*)d_in[8];

  float* out = (float*)d_out;
  int*   wsi = (int*)d_ws;
  float* wsf = (float*)d_ws;
  int* rowptr = wsi + ROWPTR_OFF;
  int* cursor = wsi + CURSOR_OFF;
  int* srcs   = wsi + SRCS_OFF;
  float* gsum = wsf + GSUM_OFF;   // becomes mean
  float* gvar = wsf + GVAR_OFF;   // becomes rstd
  float* gcnt = wsf + GCNT_OFF;

  // zero: count histogram (cursor region) + graph stats
  hipMemsetAsync(cursor, 0, 50016 * sizeof(int), stream);
  hipMemsetAsync(gsum, 0, STATS_FLOATS * sizeof(float), stream);

  // CSR build
  hist_k<<<(N_EDGES + 255) / 256, 256, 0, stream>>>(ei, cursor);
  scan_k<<<1, 1024, 0, stream>>>(cursor, rowptr, cursor);
  sort_k<<<(N_EDGES + 255) / 256, 256, 0, stream>>>(ei, cursor, srcs);

  // gather + mean into d_out
  gather_k<<<(N_NODES * 32 + 255) / 256, 256, 0, stream>>>(x, rowptr, srcs, out);

  // linear (in place on d_out)
  linear_k<<<N_NODES / 2, 256, 0, stream>>>(out, x, Wl, bl, Wr);

  // graph stats
  gcnt_hist<<<(N_NODES + 255) / 256, 256, 0, stream>>>(batch, gcnt);
  seg_reduce<0><<<(N_NODES + 63) / 64, 128, 0, stream>>>(out, batch, nullptr, nullptr, gsum);
  mean_div<<<(N_GRAPHS * HIDDEN + 255) / 256, 256, 0, stream>>>(gsum, gcnt);
  seg_reduce<1><<<(N_NODES + 63) / 64, 128, 0, stream>>>(out, batch, gsum, alpha, gvar);
  rstd_k<<<(N_GRAPHS * HIDDEN + 255) / 256, 256, 0, stream>>>(gvar, gcnt);

  // normalize + GELU + residual (in place)
  final_k<<<(N_NODES * HIDDEN / 4 + 255) / 256, 256, 0, stream>>>(
      out, x, batch, gsum, gvar, alpha, gw, gb);
}

// Round 3
// 284.492 us; speedup vs baseline: 5.7862x; 1.7638x over previous
//
#include <hip/hip_runtime.h>
#include <math.h>

#define NN 50000
#define NE 800000
#define HD 128
#define NG 32
#define GN_EPS 1e-5f

typedef __bf16 v8bf __attribute__((ext_vector_type(8)));
typedef float f32x4 __attribute__((ext_vector_type(4)));

// ---- ws layout (4-byte element offsets) ----
#define ROWPTR_OFF 0          // 50001 ints
#define CURSOR_OFF 50016      // 50016 ints (histogram, then cursors)
#define SRCS_OFF   100032     // 800000 ints
#define WPACK_OFF  900032     // 32768 ushorts = 16384 slots
#define GSUM_OFF   916480     // 4096 floats (sum -> mean)
#define GSQ_OFF    920576     // 4096 floats (sumsq -> rstd)
#define GCNT_OFF   924672     // 32 floats

__device__ __forceinline__ unsigned short f2bf(float f) {
  unsigned int u = __float_as_uint(f);
  u = (u + 0x7fffu + ((u >> 16) & 1u)) >> 16;   // RNE
  return (unsigned short)u;
}
__device__ __forceinline__ float bf_lo(unsigned int u) { return __uint_as_float(u << 16); }
__device__ __forceinline__ float bf_hi(unsigned int u) { return __uint_as_float(u & 0xffff0000u); }

// pack Wcat = [Wl; Wr] (256x128) into MFMA B-fragment order:
// Wpack[((ks*8+nt)*64+lane)*8+e] = Wcat[ks*32+(lane>>4)*8+e][nt*16+(lane&15)]
__global__ __launch_bounds__(256) void pack_w(const float* __restrict__ Wl,
    const float* __restrict__ Wr, unsigned short* __restrict__ wp) {
  int i = blockIdx.x * 256 + threadIdx.x;
  if (i >= 32768) return;
  int e = i & 7, lane = (i >> 3) & 63, nt = (i >> 9) & 7, ks = i >> 12;
  int k = ks * 32 + (lane >> 4) * 8 + e;
  int c = nt * 16 + (lane & 15);
  float v = (k < HD) ? Wl[k * HD + c] : Wr[(k - HD) * HD + c];
  wp[i] = f2bf(v);
}

// x (f32) -> bf16 into A-buffer x-half: Abuf[n*256 + 128 + d]
__global__ __launch_bounds__(256) void convert_x(const float* __restrict__ x,
                                                 unsigned short* __restrict__ Abuf) {
  int i = blockIdx.x * 256 + threadIdx.x;   // 800000 threads, 8 elems each
  if (i >= NN * 16) return;
  int n = i >> 4, seg = i & 15;
  const float* src = x + (size_t)n * HD + seg * 8;
  float4 v0 = *(const float4*)(src);
  float4 v1 = *(const float4*)(src + 4);
  uint4 o;
  o.x = (unsigned)f2bf(v0.x) | ((unsigned)f2bf(v0.y) << 16);
  o.y = (unsigned)f2bf(v0.z) | ((unsigned)f2bf(v0.w) << 16);
  o.z = (unsigned)f2bf(v1.x) | ((unsigned)f2bf(v1.y) << 16);
  o.w = (unsigned)f2bf(v1.z) | ((unsigned)f2bf(v1.w) << 16);
  *(uint4*)(Abuf + (size_t)n * 256 + 128 + seg * 8) = o;
}

__global__ __launch_bounds__(256) void hist_k(const int* __restrict__ ei,
                                              int* __restrict__ cnt) {
  int e = blockIdx.x * 256 + threadIdx.x;
  if (e >= NE) return;
  atomicAdd(&cnt[ei[NE + e]], 1);
}

__global__ __launch_bounds__(1024) void scan_k(const int* __restrict__ cnt,
                                               int* __restrict__ rowptr,
                                               int* __restrict__ cursor) {
  __shared__ int ssum[1024];
  int tid = threadIdx.x;
  const int CH = (NN + 1023) / 1024;
  int start = tid * CH;
  int end = min(start + CH, NN);
  int s = 0;
  for (int i = start; i < end; ++i) s += cnt[i];
  ssum[tid] = s;
  __syncthreads();
  for (int off = 1; off < 1024; off <<= 1) {
    int v = (tid >= off) ? ssum[tid - off] : 0;
    __syncthreads();
    ssum[tid] += v;
    __syncthreads();
  }
  int run = (tid == 0) ? 0 : ssum[tid - 1];
  for (int i = start; i < end; ++i) {
    int c = cnt[i];          // read BEFORE writing cursor[i] (aliased!)
    rowptr[i] = run;
    cursor[i] = run;
    run += c;
  }
  if (tid == 1023) rowptr[NN] = ssum[1023];
}

__global__ __launch_bounds__(256) void sort_k(const int* __restrict__ ei,
                                              int* __restrict__ cursor,
                                              int* __restrict__ srcs) {
  int e = blockIdx.x * 256 + threadIdx.x;
  if (e >= NE) return;
  int src = ei[e];
  int dst = ei[NE + e];
  int pos = atomicAdd(&cursor[dst], 1);
  srcs[pos] = src;
}

// gather bf16 x rows, mean, write bf16 agg into A-buffer agg-half (16 lanes/node)
__global__ __launch_bounds__(256) void gather_k(const int* __restrict__ rowptr,
    const int* __restrict__ srcs, unsigned short* Abuf) {
  int t = blockIdx.x * 256 + threadIdx.x;
  int n = t >> 4, q = t & 15;
  if (n >= NN) return;
  int b = rowptr[n], e = rowptr[n + 1];
  float a0=0,a1=0,a2=0,a3=0,a4=0,a5=0,a6=0,a7=0;
  int i = b;
  for (; i + 1 < e; i += 2) {
    int s0 = srcs[i], s1 = srcs[i + 1];
    uint4 v0 = *(const uint4*)(Abuf + (size_t)s0 * 256 + 128 + q * 8);
    uint4 v1 = *(const uint4*)(Abuf + (size_t)s1 * 256 + 128 + q * 8);
    a0 += bf_lo(v0.x) + bf_lo(v1.x);  a1 += bf_hi(v0.x) + bf_hi(v1.x);
    a2 += bf_lo(v0.y) + bf_lo(v1.y);  a3 += bf_hi(v0.y) + bf_hi(v1.y);
    a4 += bf_lo(v0.z) + bf_lo(v1.z);  a5 += bf_hi(v0.z) + bf_hi(v1.z);
    a6 += bf_lo(v0.w) + bf_lo(v1.w);  a7 += bf_hi(v0.w) + bf_hi(v1.w);
  }
  if (i < e) {
    int s0 = srcs[i];
    uint4 v0 = *(const uint4*)(Abuf + (size_t)s0 * 256 + 128 + q * 8);
    a0 += bf_lo(v0.x); a1 += bf_hi(v0.x);
    a2 += bf_lo(v0.y); a3 += bf_hi(v0.y);
    a4 += bf_lo(v0.z); a5 += bf_hi(v0.z);
    a6 += bf_lo(v0.w); a7 += bf_hi(v0.w);
  }
  float inv = 1.0f / fmaxf((float)(e - b), 1.0f);
  uint4 o;
  o.x = (unsigned)f2bf(a0 * inv) | ((unsigned)f2bf(a1 * inv) << 16);
  o.y = (unsigned)f2bf(a2 * inv) | ((unsigned)f2bf(a3 * inv) << 16);
  o.z = (unsigned)f2bf(a4 * inv) | ((unsigned)f2bf(a5 * inv) << 16);
  o.w = (unsigned)f2bf(a6 * inv) | ((unsigned)f2bf(a7 * inv) << 16);
  *(uint4*)(Abuf + (size_t)n * 256 + q * 8) = o;
}

// MFMA GEMM: out[n][c] = A[n][:] @ Wcat[:][c] + bl[c]; A is bf16 [NN][256] aliased
// with out f32 [NN][128] (same bytes) -- each wave reads only its own 16 rows,
// all reads complete (data dep through MFMA) before the epilogue stores.
__global__ __launch_bounds__(256) void gemm_k(const unsigned short* Abuf,
    const unsigned short* __restrict__ wp, const float* __restrict__ bl,
    float* out) {
  int wave = threadIdx.x >> 6;
  int lane = threadIdx.x & 63;
  int base = blockIdx.x * 64 + wave * 16;
  int row = lane & 15, kg = lane >> 4;
  int node = base + row;
  if (node > NN - 1) node = NN - 1;           // tail clamp (reads only)
  const unsigned short* arow = Abuf + (size_t)node * 256 + kg * 8;
  f32x4 acc[8] = {};
#pragma unroll
  for (int ks = 0; ks < 8; ++ks) {
    v8bf a = __builtin_bit_cast(v8bf, *(const uint4*)(arow + ks * 32));
    const unsigned short* wrow = wp + ks * 4096 + lane * 8;
#pragma unroll
    for (int nt = 0; nt < 8; ++nt) {
      v8bf b = __builtin_bit_cast(v8bf, *(const uint4*)(wrow + nt * 512));
      acc[nt] = __builtin_amdgcn_mfma_f32_16x16x32_bf16(a, b, acc[nt], 0, 0, 0);
    }
  }
  int c0 = lane & 15;
  float bv[8];
#pragma unroll
  for (int nt = 0; nt < 8; ++nt) bv[nt] = bl[nt * 16 + c0];
#pragma unroll
  for (int j = 0; j < 4; ++j) {
    int n = base + kg * 4 + j;
    if (n >= NN) break;
    float* orow = out + (size_t)n * HD;
#pragma unroll
    for (int nt = 0; nt < 8; ++nt) orow[nt * 16 + c0] = acc[nt][j] + bv[nt];
  }
}

__global__ __launch_bounds__(256) void gcnt_hist(const int* __restrict__ batch,
                                                 float* __restrict__ gcnt) {
  __shared__ int h[NG];
  int tid = threadIdx.x;
  if (tid < NG) h[tid] = 0;
  __syncthreads();
  int n = blockIdx.x * 256 + tid;
  if (n < NN) atomicAdd(&h[batch[n]], 1);
  __syncthreads();
  if (tid < NG && h[tid]) atomicAdd(gcnt + tid, (float)h[tid]);
}

// single pass: per-graph sum and sumsq of out
__global__ __launch_bounds__(128) void stats_k(const float* __restrict__ out,
    const int* __restrict__ batch, float* __restrict__ gsum,
    float* __restrict__ gsq) {
  int d = threadIdx.x;
  int nstart = blockIdx.x * 64;
  if (nstart >= NN) return;
  int nend = min(nstart + 64, NN);
  int cur = batch[nstart];
  float s = 0.0f, ss = 0.0f;
  for (int n = nstart; n < nend; ++n) {
    int g = batch[n];
    if (g != cur) {
      atomicAdd(gsum + cur * HD + d, s);
      atomicAdd(gsq + cur * HD + d, ss);
      s = 0.0f; ss = 0.0f; cur = g;
    }
    float v = out[(size_t)n * HD + d];
    s += v; ss += v * v;
  }
  atomicAdd(gsum + cur * HD + d, s);
  atomicAdd(gsq + cur * HD + d, ss);
}

// gsum -> mean, gsq -> rstd;  var = E[v^2] - mu^2*(2a - a^2)
__global__ __launch_bounds__(256) void finalize_k(float* __restrict__ gsum,
    float* __restrict__ gsq, const float* __restrict__ gcnt,
    const float* __restrict__ alpha) {
  int i = blockIdx.x * 256 + threadIdx.x;
  if (i >= NG * HD) return;
  int g = i >> 7, d = i & 127;
  float cnt = fmaxf(gcnt[g], 1.0f);
  float mu = gsum[i] / cnt;
  float a = alpha[d];
  float var = gsq[i] / cnt - mu * mu * (2.0f * a - a * a);
  var = fmaxf(var, 0.0f);
  gsum[i] = mu;
  gsq[i] = rsqrtf(var + GN_EPS);
}

__global__ __launch_bounds__(256) void final_k(float* __restrict__ out,
    const float* __restrict__ x, const int* __restrict__ batch,
    const float* __restrict__ mean, const float* __restrict__ rstd,
    const float* __restrict__ alpha, const float* __restrict__ gw,
    const float* __restrict__ gb) {
  size_t i = ((size_t)blockIdx.x * 256 + threadIdx.x) * 4;
  if (i >= (size_t)NN * HD) return;
  int n = (int)(i >> 7);
  int d = (int)(i & 127);
  int g = batch[n];
  float4 v  = *(float4*)(out + i);
  float4 xv = *(const float4*)(x + i);
  float4 al = *(const float4*)(alpha + d);
  float4 w  = *(const float4*)(gw + d);
  float4 b  = *(const float4*)(gb + d);
  float4 mn = *(const float4*)(mean + (size_t)g * HD + d);
  float4 rs = *(const float4*)(rstd + (size_t)g * HD + d);
  float vv[4] = {v.x, v.y, v.z, v.w};
  float xx[4] = {xv.x, xv.y, xv.z, xv.w};
  float aa[4] = {al.x, al.y, al.z, al.w};
  float ww[4] = {w.x, w.y, w.z, w.w};
  float bb[4] = {b.x, b.y, b.z, b.w};
  float mm[4] = {mn.x, mn.y, mn.z, mn.w};
  float rr[4] = {rs.x, rs.y, rs.z, rs.w};
  float r[4];
#pragma unroll
  for (int c = 0; c < 4; ++c) {
    float sub = vv[c] - aa[c] * mm[c];
    float nm  = ww[c] * sub * rr[c] + bb[c];
    float ge  = 0.5f * nm * (1.0f + erff(nm * 0.70710678118654752f));
    r[c] = ge + xx[c];
  }
  float4 res = {r[0], r[1], r[2], r[3]};
  *(float4*)(out + i) = res;
}

extern "C" void kernel_launch(void* const* d_in, const int* in_sizes, int n_in,
                              void* d_out, int out_size, void* d_ws, size_t ws_size,
                              hipStream_t stream) {
  const float* x     = (const float*)d_in[0];
  const int*   ei    = (const int*)d_in[1];
  const int*   batch = (const int*)d_in[2];
  const float* Wl    = (const float*)d_in[3];
  const float* bl    = (const float*)d_in[4];
  const float* Wr    = (const float*)d_in[5];
  const float* gw    = (const float*)d_in[6];
  const float* gb    = (const float*)d_in[7];
  const float* alpha = (const float*)d_in[8];

  float* out = (float*)d_out;
  unsigned short* Abuf = (unsigned short*)d_out;   // bf16 [NN][256] alias
  int*   wsi = (int*)d_ws;
  float* wsf = (float*)d_ws;
  int* rowptr = wsi + ROWPTR_OFF;
  int* cursor = wsi + CURSOR_OFF;
  int* srcs   = wsi + SRCS_OFF;
  unsigned short* wpack = (unsigned short*)(wsi + WPACK_OFF);
  float* gsum = wsf + GSUM_OFF;
  float* gsq  = wsf + GSQ_OFF;
  float* gcnt = wsf + GCNT_OFF;

  hipMemsetAsync(cursor, 0, 50016 * sizeof(int), stream);
  hipMemsetAsync(gsum, 0, (4096 + 4096 + 32) * sizeof(float), stream);

  pack_w<<<128, 256, 0, stream>>>(Wl, Wr, wpack);
  convert_x<<<3125, 256, 0, stream>>>(x, Abuf);

  hist_k<<<(NE + 255) / 256, 256, 0, stream>>>(ei, cursor);
  scan_k<<<1, 1024, 0, stream>>>(cursor, rowptr, cursor);
  sort_k<<<(NE + 255) / 256, 256, 0, stream>>>(ei, cursor, srcs);

  gather_k<<<(NN * 16 + 255) / 256, 256, 0, stream>>>(rowptr, srcs, Abuf);

  gemm_k<<<(NN + 63) / 64, 256, 0, stream>>>(Abuf, wpack, bl, out);

  gcnt_hist<<<(NN + 255) / 256, 256, 0, stream>>>(batch, gcnt);
  stats_k<<<(NN + 63) / 64, 128, 0, stream>>>(out, batch, gsum, gsq);
  finalize_k<<<16, 256, 0, stream>>>(gsum, gsq, gcnt, alpha);

  final_k<<<(NN * HD / 4 + 255) / 256, 256, 0, stream>>>(
      out, x, batch, gsum, gsq, alpha, gw, gb);
}

// Round 4
// 189.243 us; speedup vs baseline: 8.6985x; 1.5033x over previous
//
#include <hip/hip_runtime.h>
#include <math.h>

#define NN 50000
#define NE 800000
#define HD 128
#define NG 32
#define GN_EPS 1e-5f
#define NBLK_SCAN ((NN + 255) / 256)   // 196

typedef __bf16 v8bf __attribute__((ext_vector_type(8)));
typedef float f32x4 __attribute__((ext_vector_type(4)));

// ---- ws layout (4-byte element offsets) ----
#define ROWPTR_OFF 0          // 50001 ints
#define CURSOR_OFF 50016      // 50016 ints (histogram, then cursors)
#define SRCS_OFF   100032     // 800000 ints
#define BSUM_OFF   900032     // 256 ints
#define WPACK_OFF  900288     // 32768 ushorts = 16384 slots
#define GSUM_OFF   916736     // 4096 floats (sum -> mean)
#define GSQ_OFF    920832     // 4096 floats (sumsq -> rstd)
#define GCNT_OFF   924928     // 32 floats

__device__ __forceinline__ unsigned short f2bf(float f) {
  unsigned int u = __float_as_uint(f);
  u = (u + 0x7fffu + ((u >> 16) & 1u)) >> 16;   // RNE
  return (unsigned short)u;
}
__device__ __forceinline__ float bf_lo(unsigned int u) { return __uint_as_float(u << 16); }
__device__ __forceinline__ float bf_hi(unsigned int u) { return __uint_as_float(u & 0xffff0000u); }

// pack Wcat = [Wl; Wr] (256x128) into MFMA B-fragment order:
// Wpack[((ks*8+nt)*64+lane)*8+e] = Wcat[ks*32+(lane>>4)*8+e][nt*16+(lane&15)]
__global__ __launch_bounds__(256) void pack_w(const float* __restrict__ Wl,
    const float* __restrict__ Wr, unsigned short* __restrict__ wp) {
  int i = blockIdx.x * 256 + threadIdx.x;
  if (i >= 32768) return;
  int e = i & 7, lane = (i >> 3) & 63, nt = (i >> 9) & 7, ks = i >> 12;
  int k = ks * 32 + (lane >> 4) * 8 + e;
  int c = nt * 16 + (lane & 15);
  float v = (k < HD) ? Wl[k * HD + c] : Wr[(k - HD) * HD + c];
  wp[i] = f2bf(v);
}

// x (f32) -> bf16 into A-buffer x-half: Abuf[n*256 + 128 + d]
__global__ __launch_bounds__(256) void convert_x(const float* __restrict__ x,
                                                 unsigned short* __restrict__ Abuf) {
  int i = blockIdx.x * 256 + threadIdx.x;
  if (i >= NN * 16) return;
  int n = i >> 4, seg = i & 15;
  const float* src = x + (size_t)n * HD + seg * 8;
  float4 v0 = *(const float4*)(src);
  float4 v1 = *(const float4*)(src + 4);
  uint4 o;
  o.x = (unsigned)f2bf(v0.x) | ((unsigned)f2bf(v0.y) << 16);
  o.y = (unsigned)f2bf(v0.z) | ((unsigned)f2bf(v0.w) << 16);
  o.z = (unsigned)f2bf(v1.x) | ((unsigned)f2bf(v1.y) << 16);
  o.w = (unsigned)f2bf(v1.z) | ((unsigned)f2bf(v1.w) << 16);
  *(uint4*)(Abuf + (size_t)n * 256 + 128 + seg * 8) = o;
}

__global__ __launch_bounds__(256) void hist_k(const int* __restrict__ ei,
                                              int* __restrict__ cnt) {
  int e = blockIdx.x * 256 + threadIdx.x;
  if (e >= NE) return;
  atomicAdd(&cnt[ei[NE + e]], 1);
}

// hierarchical scan stage 1: per-block sums of cnt
__global__ __launch_bounds__(256) void blocksum_k(const int* __restrict__ cnt,
                                                  int* __restrict__ bsum) {
  __shared__ int red[4];
  int i = blockIdx.x * 256 + threadIdx.x;
  int v = (i < NN) ? cnt[i] : 0;
#pragma unroll
  for (int off = 32; off; off >>= 1) v += __shfl_down(v, off, 64);
  int wv = threadIdx.x >> 6;
  if ((threadIdx.x & 63) == 0) red[wv] = v;
  __syncthreads();
  if (threadIdx.x == 0) bsum[blockIdx.x] = red[0] + red[1] + red[2] + red[3];
}

// stage 2: exclusive scan of NBLK_SCAN block sums (single tiny block)
__global__ __launch_bounds__(256) void scan_bsum_k(int* __restrict__ bsum) {
  __shared__ int s[256];
  int t = threadIdx.x;
  int v = (t < NBLK_SCAN) ? bsum[t] : 0;
  s[t] = v;
  __syncthreads();
#pragma unroll
  for (int off = 1; off < 256; off <<= 1) {
    int u = (t >= off) ? s[t - off] : 0;
    __syncthreads();
    s[t] += u;
    __syncthreads();
  }
  if (t < NBLK_SCAN) bsum[t] = s[t] - v;   // exclusive
}

// stage 3: in-block exclusive scan + block prefix -> rowptr, cursor
__global__ __launch_bounds__(256) void fill_k(const int* __restrict__ cnt,
    const int* __restrict__ bsum, int* __restrict__ rowptr,
    int* __restrict__ cursor) {
  __shared__ int s[256];
  int t = threadIdx.x;
  int i = blockIdx.x * 256 + t;
  int c = (i < NN) ? cnt[i] : 0;   // read before cursor write (aliased buffers)
  s[t] = c;
  __syncthreads();
#pragma unroll
  for (int off = 1; off < 256; off <<= 1) {
    int u = (t >= off) ? s[t - off] : 0;
    __syncthreads();
    s[t] += u;
    __syncthreads();
  }
  int pre = bsum[blockIdx.x] + s[t] - c;   // exclusive
  if (i < NN) {
    rowptr[i] = pre;
    cursor[i] = pre;
  }
  if (i == NN - 1) rowptr[NN] = NE;
}

__global__ __launch_bounds__(256) void sort_k(const int* __restrict__ ei,
                                              int* __restrict__ cursor,
                                              int* __restrict__ srcs) {
  int e = blockIdx.x * 256 + threadIdx.x;
  if (e >= NE) return;
  int src = ei[e];
  int dst = ei[NE + e];
  int pos = atomicAdd(&cursor[dst], 1);
  srcs[pos] = src;
}

// gather bf16 x rows, mean, write bf16 agg into A-buffer agg-half (16 lanes/node)
__global__ __launch_bounds__(256) void gather_k(const int* __restrict__ rowptr,
    const int* __restrict__ srcs, unsigned short* Abuf) {
  int t = blockIdx.x * 256 + threadIdx.x;
  int n = t >> 4, q = t & 15;
  if (n >= NN) return;
  int b = rowptr[n], e = rowptr[n + 1];
  float a0=0,a1=0,a2=0,a3=0,a4=0,a5=0,a6=0,a7=0;
  int i = b;
  for (; i + 1 < e; i += 2) {
    int s0 = srcs[i], s1 = srcs[i + 1];
    uint4 v0 = *(const uint4*)(Abuf + (size_t)s0 * 256 + 128 + q * 8);
    uint4 v1 = *(const uint4*)(Abuf + (size_t)s1 * 256 + 128 + q * 8);
    a0 += bf_lo(v0.x) + bf_lo(v1.x);  a1 += bf_hi(v0.x) + bf_hi(v1.x);
    a2 += bf_lo(v0.y) + bf_lo(v1.y);  a3 += bf_hi(v0.y) + bf_hi(v1.y);
    a4 += bf_lo(v0.z) + bf_lo(v1.z);  a5 += bf_hi(v0.z) + bf_hi(v1.z);
    a6 += bf_lo(v0.w) + bf_lo(v1.w);  a7 += bf_hi(v0.w) + bf_hi(v1.w);
  }
  if (i < e) {
    int s0 = srcs[i];
    uint4 v0 = *(const uint4*)(Abuf + (size_t)s0 * 256 + 128 + q * 8);
    a0 += bf_lo(v0.x); a1 += bf_hi(v0.x);
    a2 += bf_lo(v0.y); a3 += bf_hi(v0.y);
    a4 += bf_lo(v0.z); a5 += bf_hi(v0.z);
    a6 += bf_lo(v0.w); a7 += bf_hi(v0.w);
  }
  float inv = 1.0f / fmaxf((float)(e - b), 1.0f);
  uint4 o;
  o.x = (unsigned)f2bf(a0 * inv) | ((unsigned)f2bf(a1 * inv) << 16);
  o.y = (unsigned)f2bf(a2 * inv) | ((unsigned)f2bf(a3 * inv) << 16);
  o.z = (unsigned)f2bf(a4 * inv) | ((unsigned)f2bf(a5 * inv) << 16);
  o.w = (unsigned)f2bf(a6 * inv) | ((unsigned)f2bf(a7 * inv) << 16);
  *(uint4*)(Abuf + (size_t)n * 256 + q * 8) = o;
}

// MFMA GEMM: out[n][c] = A[n][:] @ Wcat[:][c] + bl[c]; A bf16 [NN][256] aliases
// out f32 [NN][128] (same bytes); each wave reads only its own 16 rows.
__global__ __launch_bounds__(256) void gemm_k(const unsigned short* Abuf,
    const unsigned short* __restrict__ wp, const float* __restrict__ bl,
    float* out) {
  int wave = threadIdx.x >> 6;
  int lane = threadIdx.x & 63;
  int base = blockIdx.x * 64 + wave * 16;
  int row = lane & 15, kg = lane >> 4;
  int node = base + row;
  if (node > NN - 1) node = NN - 1;
  const unsigned short* arow = Abuf + (size_t)node * 256 + kg * 8;
  f32x4 acc[8] = {};
#pragma unroll
  for (int ks = 0; ks < 8; ++ks) {
    v8bf a = __builtin_bit_cast(v8bf, *(const uint4*)(arow + ks * 32));
    const unsigned short* wrow = wp + ks * 4096 + lane * 8;
#pragma unroll
    for (int nt = 0; nt < 8; ++nt) {
      v8bf b = __builtin_bit_cast(v8bf, *(const uint4*)(wrow + nt * 512));
      acc[nt] = __builtin_amdgcn_mfma_f32_16x16x32_bf16(a, b, acc[nt], 0, 0, 0);
    }
  }
  int c0 = lane & 15;
  float bv[8];
#pragma unroll
  for (int nt = 0; nt < 8; ++nt) bv[nt] = bl[nt * 16 + c0];
#pragma unroll
  for (int j = 0; j < 4; ++j) {
    int n = base + kg * 4 + j;
    if (n >= NN) break;
    float* orow = out + (size_t)n * HD;
#pragma unroll
    for (int nt = 0; nt < 8; ++nt) orow[nt * 16 + c0] = acc[nt][j] + bv[nt];
  }
}

__global__ __launch_bounds__(256) void gcnt_hist(const int* __restrict__ batch,
                                                 float* __restrict__ gcnt) {
  __shared__ int h[NG];
  int tid = threadIdx.x;
  if (tid < NG) h[tid] = 0;
  __syncthreads();
  int n = blockIdx.x * 256 + tid;
  if (n < NN) atomicAdd(&h[batch[n]], 1);
  __syncthreads();
  if (tid < NG && h[tid]) atomicAdd(gcnt + tid, (float)h[tid]);
}

// single pass: per-graph sum and sumsq of out
__global__ __launch_bounds__(128) void stats_k(const float* __restrict__ out,
    const int* __restrict__ batch, float* __restrict__ gsum,
    float* __restrict__ gsq) {
  int d = threadIdx.x;
  int nstart = blockIdx.x * 64;
  if (nstart >= NN) return;
  int nend = min(nstart + 64, NN);
  int cur = batch[nstart];
  float s = 0.0f, ss = 0.0f;
  for (int n = nstart; n < nend; ++n) {
    int g = batch[n];
    if (g != cur) {
      atomicAdd(gsum + cur * HD + d, s);
      atomicAdd(gsq + cur * HD + d, ss);
      s = 0.0f; ss = 0.0f; cur = g;
    }
    float v = out[(size_t)n * HD + d];
    s += v; ss += v * v;
  }
  atomicAdd(gsum + cur * HD + d, s);
  atomicAdd(gsq + cur * HD + d, ss);
}

// gsum -> mean, gsq -> rstd;  var = E[v^2] - mu^2*(2a - a^2)
__global__ __launch_bounds__(256) void finalize_k(float* __restrict__ gsum,
    float* __restrict__ gsq, const float* __restrict__ gcnt,
    const float* __restrict__ alpha) {
  int i = blockIdx.x * 256 + threadIdx.x;
  if (i >= NG * HD) return;
  int g = i >> 7, d = i & 127;
  float cnt = fmaxf(gcnt[g], 1.0f);
  float mu = gsum[i] / cnt;
  float a = alpha[d];
  float var = gsq[i] / cnt - mu * mu * (2.0f * a - a * a);
  var = fmaxf(var, 0.0f);
  gsum[i] = mu;
  gsq[i] = rsqrtf(var + GN_EPS);
}

__global__ __launch_bounds__(256) void final_k(float* __restrict__ out,
    const float* __restrict__ x, const int* __restrict__ batch,
    const float* __restrict__ mean, const float* __restrict__ rstd,
    const float* __restrict__ alpha, const float* __restrict__ gw,
    const float* __restrict__ gb) {
  size_t i = ((size_t)blockIdx.x * 256 + threadIdx.x) * 4;
  if (i >= (size_t)NN * HD) return;
  int n = (int)(i >> 7);
  int d = (int)(i & 127);
  int g = batch[n];
  float4 v  = *(float4*)(out + i);
  float4 xv = *(const float4*)(x + i);
  float4 al = *(const float4*)(alpha + d);
  float4 w  = *(const float4*)(gw + d);
  float4 b  = *(const float4*)(gb + d);
  float4 mn = *(const float4*)(mean + (size_t)g * HD + d);
  float4 rs = *(const float4*)(rstd + (size_t)g * HD + d);
  float vv[4] = {v.x, v.y, v.z, v.w};
  float xx[4] = {xv.x, xv.y, xv.z, xv.w};
  float aa[4] = {al.x, al.y, al.z, al.w};
  float ww[4] = {w.x, w.y, w.z, w.w};
  float bb[4] = {b.x, b.y, b.z, b.w};
  float mm[4] = {mn.x, mn.y, mn.z, mn.w};
  float rr[4] = {rs.x, rs.y, rs.z, rs.w};
  float r[4];
#pragma unroll
  for (int c = 0; c < 4; ++c) {
    float sub = vv[c] - aa[c] * mm[c];
    float nm  = ww[c] * sub * rr[c] + bb[c];
    float ge  = 0.5f * nm * (1.0f + erff(nm * 0.70710678118654752f));
    r[c] = ge + xx[c];
  }
  float4 res = {r[0], r[1], r[2], r[3]};
  *(float4*)(out + i) = res;
}

extern "C" void kernel_launch(void* const* d_in, const int* in_sizes, int n_in,
                              void* d_out, int out_size, void* d_ws, size_t ws_size,
                              hipStream_t stream) {
  const float* x     = (const float*)d_in[0];
  const int*   ei    = (const int*)d_in[1];
  const int*   batch = (const int*)d_in[2];
  const float* Wl    = (const float*)d_in[3];
  const float* bl    = (const float*)d_in[4];
  const float* Wr    = (const float*)d_in[5];
  const float* gw    = (const float*)d_in[6];
  const float* gb    = (const float*)d_in[7];
  const float* alpha = (const float*)d_in[8];

  float* out = (float*)d_out;
  unsigned short* Abuf = (unsigned short*)d_out;   // bf16 [NN][256] alias
  int*   wsi = (int*)d_ws;
  float* wsf = (float*)d_ws;
  int* rowptr = wsi + ROWPTR_OFF;
  int* cursor = wsi + CURSOR_OFF;
  int* srcs   = wsi + SRCS_OFF;
  int* bsum   = wsi + BSUM_OFF;
  unsigned short* wpack = (unsigned short*)(wsi + WPACK_OFF);
  float* gsum = wsf + GSUM_OFF;
  float* gsq  = wsf + GSQ_OFF;
  float* gcnt = wsf + GCNT_OFF;

  hipMemsetAsync(cursor, 0, 50016 * sizeof(int), stream);
  hipMemsetAsync(gsum, 0, (4096 + 4096 + 32) * sizeof(float), stream);

  pack_w<<<128, 256, 0, stream>>>(Wl, Wr, wpack);
  convert_x<<<3125, 256, 0, stream>>>(x, Abuf);

  hist_k<<<(NE + 255) / 256, 256, 0, stream>>>(ei, cursor);
  blocksum_k<<<NBLK_SCAN, 256, 0, stream>>>(cursor, bsum);
  scan_bsum_k<<<1, 256, 0, stream>>>(bsum);
  fill_k<<<NBLK_SCAN, 256, 0, stream>>>(cursor, bsum, rowptr, cursor);
  sort_k<<<(NE + 255) / 256, 256, 0, stream>>>(ei, cursor, srcs);

  gather_k<<<(NN * 16 + 255) / 256, 256, 0, stream>>>(rowptr, srcs, Abuf);

  gemm_k<<<(NN + 63) / 64, 256, 0, stream>>>(Abuf, wpack, bl, out);

  gcnt_hist<<<(NN + 255) / 256, 256, 0, stream>>>(batch, gcnt);
  stats_k<<<(NN + 63) / 64, 128, 0, stream>>>(out, batch, gsum, gsq);
  finalize_k<<<16, 256, 0, stream>>>(gsum, gsq, gcnt, alpha);

  final_k<<<(NN * HD / 4 + 255) / 256, 256, 0, stream>>>(
      out, x, batch, gsum, gsq, alpha, gw, gb);
}

// Round 5
// 173.575 us; speedup vs baseline: 9.4836x; 1.0903x over previous
//
#include <hip/hip_runtime.h>
#include <math.h>

#define NN 50000
#define NE 800000
#define HD 128
#define NG 32
#define GN_EPS 1e-5f
#define NBLK_SCAN ((NN + 255) / 256)   // 196
#define NSH 8
#define SHW (NN / NSH)                 // 6250 nodes per shard
#define NB_SHARD 128                   // blocks per shard (hist/sort)

typedef __bf16 v8bf __attribute__((ext_vector_type(8)));
typedef float f32x4 __attribute__((ext_vector_type(4)));

// ---- ws layout (4-byte element offsets) ----
// [rowptr][cursor/cnt | gsum | gsq | gcnt]  <- one contiguous memset region
#define ROWPTR_OFF 0          // 50001 ints
#define CURSOR_OFF 50016      // 50016 ints (histogram, then cursors)
#define GSUM_OFF   100032     // 4096 floats (per-graph sum)
#define GSQ_OFF    104128     // 4096 floats (per-graph sumsq)
#define GCNT_OFF   108224     // 32 floats
#define SRCS_OFF   108256     // 800000 ushorts = 400000 ints
#define BSUM_OFF   508256     // 256 ints
#define WPACK_OFF  508512     // 32768 ushorts = 16384 ints
#define MEMSET_INTS (50016 + 4096 + 4096 + 32)   // from CURSOR_OFF

__device__ __forceinline__ unsigned short f2bf(float f) {
  unsigned int u = __float_as_uint(f);
  u = (u + 0x7fffu + ((u >> 16) & 1u)) >> 16;   // RNE
  return (unsigned short)u;
}
__device__ __forceinline__ float bf_lo(unsigned int u) { return __uint_as_float(u << 16); }
__device__ __forceinline__ float bf_hi(unsigned int u) { return __uint_as_float(u & 0xffff0000u); }

// fused: pack Wcat=[Wl;Wr] into MFMA B-frag order  +  x f32 -> bf16 Abuf x-half
__global__ __launch_bounds__(256) void prep_k(const float* __restrict__ x,
    const float* __restrict__ Wl, const float* __restrict__ Wr,
    unsigned short* __restrict__ Abuf, unsigned short* __restrict__ wp) {
  int i = blockIdx.x * 256 + threadIdx.x;
  if (i < 32768) {
    int e = i & 7, lane = (i >> 3) & 63, nt = (i >> 9) & 7, ks = i >> 12;
    int k = ks * 32 + (lane >> 4) * 8 + e;
    int c = nt * 16 + (lane & 15);
    float v = (k < HD) ? Wl[k * HD + c] : Wr[(k - HD) * HD + c];
    wp[i] = f2bf(v);
  }
  if (i < NN * 16) {
    int n = i >> 4, seg = i & 15;
    const float* src = x + (size_t)n * HD + seg * 8;
    float4 v0 = *(const float4*)(src);
    float4 v1 = *(const float4*)(src + 4);
    uint4 o;
    o.x = (unsigned)f2bf(v0.x) | ((unsigned)f2bf(v0.y) << 16);
    o.y = (unsigned)f2bf(v0.z) | ((unsigned)f2bf(v0.w) << 16);
    o.z = (unsigned)f2bf(v1.x) | ((unsigned)f2bf(v1.y) << 16);
    o.w = (unsigned)f2bf(v1.z) | ((unsigned)f2bf(v1.w) << 16);
    *(uint4*)(Abuf + (size_t)n * 256 + 128 + seg * 8) = o;
  }
}

// XCD-sharded histogram: shard = blockIdx&7 (round-robin XCD), each shard
// scans all dst's but only counts its own range -> cnt lines stay XCD-local.
__global__ __launch_bounds__(256) void hist_k(const int* __restrict__ ei,
                                              int* __restrict__ cnt) {
  int shard = blockIdx.x & 7;
  int blk = blockIdx.x >> 3;
  int lo = shard * SHW, hi = lo + SHW;
  for (int e = blk * 256 + threadIdx.x; e < NE; e += NB_SHARD * 256) {
    int dst = ei[NE + e];
    if (dst >= lo && dst < hi) atomicAdd(&cnt[dst], 1);
  }
}

// hierarchical scan stage 1: per-block sums of cnt
__global__ __launch_bounds__(256) void blocksum_k(const int* __restrict__ cnt,
                                                  int* __restrict__ bsum) {
  __shared__ int red[4];
  int i = blockIdx.x * 256 + threadIdx.x;
  int v = (i < NN) ? cnt[i] : 0;
#pragma unroll
  for (int off = 32; off; off >>= 1) v += __shfl_down(v, off, 64);
  int wv = threadIdx.x >> 6;
  if ((threadIdx.x & 63) == 0) red[wv] = v;
  __syncthreads();
  if (threadIdx.x == 0) bsum[blockIdx.x] = red[0] + red[1] + red[2] + red[3];
}

// stage 2: exclusive scan of block sums (single tiny block)
__global__ __launch_bounds__(256) void scan_bsum_k(int* __restrict__ bsum) {
  __shared__ int s[256];
  int t = threadIdx.x;
  int v = (t < NBLK_SCAN) ? bsum[t] : 0;
  s[t] = v;
  __syncthreads();
#pragma unroll
  for (int off = 1; off < 256; off <<= 1) {
    int u = (t >= off) ? s[t - off] : 0;
    __syncthreads();
    s[t] += u;
    __syncthreads();
  }
  if (t < NBLK_SCAN) bsum[t] = s[t] - v;   // exclusive
}

// stage 3: in-block exclusive scan + block prefix -> rowptr, cursor
__global__ __launch_bounds__(256) void fill_k(const int* __restrict__ cnt,
    const int* __restrict__ bsum, int* __restrict__ rowptr,
    int* __restrict__ cursor) {
  __shared__ int s[256];
  int t = threadIdx.x;
  int i = blockIdx.x * 256 + t;
  int c = (i < NN) ? cnt[i] : 0;   // read before cursor write (aliased)
  s[t] = c;
  __syncthreads();
#pragma unroll
  for (int off = 1; off < 256; off <<= 1) {
    int u = (t >= off) ? s[t - off] : 0;
    __syncthreads();
    s[t] += u;
    __syncthreads();
  }
  int pre = bsum[blockIdx.x] + s[t] - c;
  if (i < NN) {
    rowptr[i] = pre;
    cursor[i] = pre;
  }
  if (i == NN - 1) rowptr[NN] = NE;
}

// XCD-sharded counting sort: srcs (ushort) lines written by one XCD only.
__global__ __launch_bounds__(256) void sort_k(const int* __restrict__ ei,
    int* __restrict__ cursor, unsigned short* __restrict__ srcs) {
  int shard = blockIdx.x & 7;
  int blk = blockIdx.x >> 3;
  int lo = shard * SHW, hi = lo + SHW;
  for (int e = blk * 256 + threadIdx.x; e < NE; e += NB_SHARD * 256) {
    int dst = ei[NE + e];
    if (dst >= lo && dst < hi) {
      int pos = atomicAdd(&cursor[dst], 1);
      srcs[pos] = (unsigned short)ei[e];
    }
  }
}

// gather bf16 x rows, mean, write bf16 agg into A-buffer agg-half (16 lanes/node)
__global__ __launch_bounds__(256) void gather_k(const int* __restrict__ rowptr,
    const unsigned short* __restrict__ srcs, unsigned short* Abuf) {
  int t = blockIdx.x * 256 + threadIdx.x;
  int n = t >> 4, q = t & 15;
  if (n >= NN) return;
  int b = rowptr[n], e = rowptr[n + 1];
  float a0=0,a1=0,a2=0,a3=0,a4=0,a5=0,a6=0,a7=0;
  int i = b;
  for (; i + 1 < e; i += 2) {
    int s0 = srcs[i], s1 = srcs[i + 1];
    uint4 v0 = *(const uint4*)(Abuf + (size_t)s0 * 256 + 128 + q * 8);
    uint4 v1 = *(const uint4*)(Abuf + (size_t)s1 * 256 + 128 + q * 8);
    a0 += bf_lo(v0.x) + bf_lo(v1.x);  a1 += bf_hi(v0.x) + bf_hi(v1.x);
    a2 += bf_lo(v0.y) + bf_lo(v1.y);  a3 += bf_hi(v0.y) + bf_hi(v1.y);
    a4 += bf_lo(v0.z) + bf_lo(v1.z);  a5 += bf_hi(v0.z) + bf_hi(v1.z);
    a6 += bf_lo(v0.w) + bf_lo(v1.w);  a7 += bf_hi(v0.w) + bf_hi(v1.w);
  }
  if (i < e) {
    int s0 = srcs[i];
    uint4 v0 = *(const uint4*)(Abuf + (size_t)s0 * 256 + 128 + q * 8);
    a0 += bf_lo(v0.x); a1 += bf_hi(v0.x);
    a2 += bf_lo(v0.y); a3 += bf_hi(v0.y);
    a4 += bf_lo(v0.z); a5 += bf_hi(v0.z);
    a6 += bf_lo(v0.w); a7 += bf_hi(v0.w);
  }
  float inv = 1.0f / fmaxf((float)(e - b), 1.0f);
  uint4 o;
  o.x = (unsigned)f2bf(a0 * inv) | ((unsigned)f2bf(a1 * inv) << 16);
  o.y = (unsigned)f2bf(a2 * inv) | ((unsigned)f2bf(a3 * inv) << 16);
  o.z = (unsigned)f2bf(a4 * inv) | ((unsigned)f2bf(a5 * inv) << 16);
  o.w = (unsigned)f2bf(a6 * inv) | ((unsigned)f2bf(a7 * inv) << 16);
  *(uint4*)(Abuf + (size_t)n * 256 + q * 8) = o;
}

// MFMA GEMM: out[n][c] = A[n][:] @ Wcat[:][c] + bl[c]; A bf16 [NN][256] aliases
// out f32 [NN][128] (same bytes); each wave reads only its own 16 rows.
__global__ __launch_bounds__(256) void gemm_k(const unsigned short* Abuf,
    const unsigned short* __restrict__ wp, const float* __restrict__ bl,
    float* out) {
  int wave = threadIdx.x >> 6;
  int lane = threadIdx.x & 63;
  int base = blockIdx.x * 64 + wave * 16;
  int row = lane & 15, kg = lane >> 4;
  int node = base + row;
  if (node > NN - 1) node = NN - 1;
  const unsigned short* arow = Abuf + (size_t)node * 256 + kg * 8;
  f32x4 acc[8] = {};
#pragma unroll
  for (int ks = 0; ks < 8; ++ks) {
    v8bf a = __builtin_bit_cast(v8bf, *(const uint4*)(arow + ks * 32));
    const unsigned short* wrow = wp + ks * 4096 + lane * 8;
#pragma unroll
    for (int nt = 0; nt < 8; ++nt) {
      v8bf b = __builtin_bit_cast(v8bf, *(const uint4*)(wrow + nt * 512));
      acc[nt] = __builtin_amdgcn_mfma_f32_16x16x32_bf16(a, b, acc[nt], 0, 0, 0);
    }
  }
  int c0 = lane & 15;
  float bv[8];
#pragma unroll
  for (int nt = 0; nt < 8; ++nt) bv[nt] = bl[nt * 16 + c0];
#pragma unroll
  for (int j = 0; j < 4; ++j) {
    int n = base + kg * 4 + j;
    if (n >= NN) break;
    float* orow = out + (size_t)n * HD;
#pragma unroll
    for (int nt = 0; nt < 8; ++nt) orow[nt * 16 + c0] = acc[nt][j] + bv[nt];
  }
}

// single pass: per-graph sum, sumsq of out + node counts (thread 0)
__global__ __launch_bounds__(128) void stats_k(const float* __restrict__ out,
    const int* __restrict__ batch, float* __restrict__ gsum,
    float* __restrict__ gsq, float* __restrict__ gcnt) {
  int d = threadIdx.x;
  int nstart = blockIdx.x * 64;
  if (nstart >= NN) return;
  int nend = min(nstart + 64, NN);
  int cur = batch[nstart];
  float s = 0.0f, ss = 0.0f;
  int run = 0;
  for (int n = nstart; n < nend; ++n) {
    int g = batch[n];
    if (g != cur) {
      atomicAdd(gsum + cur * HD + d, s);
      atomicAdd(gsq + cur * HD + d, ss);
      if (d == 0) atomicAdd(gcnt + cur, (float)run);
      s = 0.0f; ss = 0.0f; run = 0; cur = g;
    }
    float v = out[(size_t)n * HD + d];
    s += v; ss += v * v; run++;
  }
  atomicAdd(gsum + cur * HD + d, s);
  atomicAdd(gsq + cur * HD + d, ss);
  if (d == 0) atomicAdd(gcnt + cur, (float)run);
}

// fused: mean/rstd from raw sums (tiny hot region) + norm + GELU + residual
__global__ __launch_bounds__(256) void final_k(float* __restrict__ out,
    const float* __restrict__ x, const int* __restrict__ batch,
    const float* __restrict__ gsum, const float* __restrict__ gsq,
    const float* __restrict__ gcnt, const float* __restrict__ alpha,
    const float* __restrict__ gw, const float* __restrict__ gb) {
  size_t i = ((size_t)blockIdx.x * 256 + threadIdx.x) * 4;
  if (i >= (size_t)NN * HD) return;
  int n = (int)(i >> 7);
  int d = (int)(i & 127);
  int g = batch[n];
  float cinv = 1.0f / fmaxf(gcnt[g], 1.0f);
  float4 v  = *(float4*)(out + i);
  float4 xv = *(const float4*)(x + i);
  float4 al = *(const float4*)(alpha + d);
  float4 w  = *(const float4*)(gw + d);
  float4 b  = *(const float4*)(gb + d);
  float4 sm = *(const float4*)(gsum + (size_t)g * HD + d);
  float4 sq = *(const float4*)(gsq + (size_t)g * HD + d);
  float vv[4] = {v.x, v.y, v.z, v.w};
  float xx[4] = {xv.x, xv.y, xv.z, xv.w};
  float aa[4] = {al.x, al.y, al.z, al.w};
  float ww[4] = {w.x, w.y, w.z, w.w};
  float bb[4] = {b.x, b.y, b.z, b.w};
  float mm[4] = {sm.x, sm.y, sm.z, sm.w};
  float qq[4] = {sq.x, sq.y, sq.z, sq.w};
  float r[4];
#pragma unroll
  for (int c = 0; c < 4; ++c) {
    float mu = mm[c] * cinv;
    float a = aa[c];
    float var = qq[c] * cinv - mu * mu * (2.0f * a - a * a);
    float rs = rsqrtf(fmaxf(var, 0.0f) + GN_EPS);
    float sub = vv[c] - a * mu;
    float nm  = ww[c] * sub * rs + bb[c];
    float ge  = 0.5f * nm * (1.0f + erff(nm * 0.70710678118654752f));
    r[c] = ge + xx[c];
  }
  float4 res = {r[0], r[1], r[2], r[3]};
  *(float4*)(out + i) = res;
}

extern "C" void kernel_launch(void* const* d_in, const int* in_sizes, int n_in,
                              void* d_out, int out_size, void* d_ws, size_t ws_size,
                              hipStream_t stream) {
  const float* x     = (const float*)d_in[0];
  const int*   ei    = (const int*)d_in[1];
  const int*   batch = (const int*)d_in[2];
  const float* Wl    = (const float*)d_in[3];
  const float* bl    = (const float*)d_in[4];
  const float* Wr    = (const float*)d_in[5];
  const float* gw    = (const float*)d_in[6];
  const float* gb    = (const float*)d_in[7];
  const float* alpha = (const float*)d_in[8];

  float* out = (float*)d_out;
  unsigned short* Abuf = (unsigned short*)d_out;   // bf16 [NN][256] alias
  int*   wsi = (int*)d_ws;
  float* wsf = (float*)d_ws;
  int* rowptr = wsi + ROWPTR_OFF;
  int* cursor = wsi + CURSOR_OFF;
  float* gsum = wsf + GSUM_OFF;
  float* gsq  = wsf + GSQ_OFF;
  float* gcnt = wsf + GCNT_OFF;
  unsigned short* srcs = (unsigned short*)(wsi + SRCS_OFF);
  int* bsum   = wsi + BSUM_OFF;
  unsigned short* wpack = (unsigned short*)(wsi + WPACK_OFF);

  hipMemsetAsync(cursor, 0, MEMSET_INTS * sizeof(int), stream);

  prep_k<<<3125, 256, 0, stream>>>(x, Wl, Wr, Abuf, wpack);

  hist_k<<<NSH * NB_SHARD, 256, 0, stream>>>(ei, cursor);
  blocksum_k<<<NBLK_SCAN, 256, 0, stream>>>(cursor, bsum);
  scan_bsum_k<<<1, 256, 0, stream>>>(bsum);
  fill_k<<<NBLK_SCAN, 256, 0, stream>>>(cursor, bsum, rowptr, cursor);
  sort_k<<<NSH * NB_SHARD, 256, 0, stream>>>(ei, cursor, srcs);

  gather_k<<<(NN * 16 + 255) / 256, 256, 0, stream>>>(rowptr, srcs, Abuf);

  gemm_k<<<(NN + 63) / 64, 256, 0, stream>>>(Abuf, wpack, bl, out);

  stats_k<<<(NN + 63) / 64, 128, 0, stream>>>(out, batch, gsum, gsq, gcnt);

  final_k<<<(NN * HD / 4 + 255) / 256, 256, 0, stream>>>(
      out, x, batch, gsum, gsq, gcnt, alpha, gw, gb);
}

// Round 6
// 167.892 us; speedup vs baseline: 9.8047x; 1.0339x over previous
//
#include <hip/hip_runtime.h>
#include <math.h>

#define NN 50000
#define NE 800000
#define HD 128
#define NG 32
#define GN_EPS 1e-5f
#define NBLK_SCAN ((NN + 255) / 256)   // 196
#define NSH 8
#define SHW (NN / NSH)                 // 6250 nodes per shard
#define NB_SHARD 128                   // blocks per shard (hist/sort)

typedef __bf16 v8bf __attribute__((ext_vector_type(8)));
typedef float f32x4 __attribute__((ext_vector_type(4)));

// ---- ws layout (4-byte element offsets) ----
// [rowptr][cursor/cnt | gsum | gsq | gcnt]  <- one contiguous zeroed region
#define ROWPTR_OFF 0          // 50001 ints
#define CURSOR_OFF 50016      // 50016 ints (histogram, then cursors)
#define GSUM_OFF   100032     // 4096 floats (per-graph sum)
#define GSQ_OFF    104128     // 4096 floats (per-graph sumsq)
#define GCNT_OFF   108224     // 32 floats
#define SRCS_OFF   108256     // 800000 ushorts = 400000 ints
#define BSUM_OFF   508256     // 256 ints
#define WPACK_OFF  508512     // 32768 ushorts = 16384 ints
#define MEMSET_INTS (50016 + 4096 + 4096 + 32)   // from CURSOR_OFF, = 58240

__device__ __forceinline__ unsigned short f2bf(float f) {
  unsigned int u = __float_as_uint(f);
  u = (u + 0x7fffu + ((u >> 16) & 1u)) >> 16;   // RNE
  return (unsigned short)u;
}
__device__ __forceinline__ float bf_lo(unsigned int u) { return __uint_as_float(u << 16); }
__device__ __forceinline__ float bf_hi(unsigned int u) { return __uint_as_float(u & 0xffff0000u); }

// fused: zero scratch region + pack Wcat=[Wl;Wr] into MFMA B-frag order
//        + x f32 -> bf16 Abuf x-half
// (zeroing a hipMemsetAsync graph node cost 41us/replay -- ROCm small-fill
//  pathology; doing it here on an already-launched 800K-thread grid is ~free)
__global__ __launch_bounds__(256) void prep_k(const float* __restrict__ x,
    const float* __restrict__ Wl, const float* __restrict__ Wr,
    unsigned short* __restrict__ Abuf, unsigned short* __restrict__ wp,
    int* __restrict__ zbase) {
  int i = blockIdx.x * 256 + threadIdx.x;
  if (i < MEMSET_INTS) zbase[i] = 0;
  if (i < 32768) {
    int e = i & 7, lane = (i >> 3) & 63, nt = (i >> 9) & 7, ks = i >> 12;
    int k = ks * 32 + (lane >> 4) * 8 + e;
    int c = nt * 16 + (lane & 15);
    float v = (k < HD) ? Wl[k * HD + c] : Wr[(k - HD) * HD + c];
    wp[i] = f2bf(v);
  }
  if (i < NN * 16) {
    int n = i >> 4, seg = i & 15;
    const float* src = x + (size_t)n * HD + seg * 8;
    float4 v0 = *(const float4*)(src);
    float4 v1 = *(const float4*)(src + 4);
    uint4 o;
    o.x = (unsigned)f2bf(v0.x) | ((unsigned)f2bf(v0.y) << 16);
    o.y = (unsigned)f2bf(v0.z) | ((unsigned)f2bf(v0.w) << 16);
    o.z = (unsigned)f2bf(v1.x) | ((unsigned)f2bf(v1.y) << 16);
    o.w = (unsigned)f2bf(v1.z) | ((unsigned)f2bf(v1.w) << 16);
    *(uint4*)(Abuf + (size_t)n * 256 + 128 + seg * 8) = o;
  }
}

// XCD-sharded histogram: shard = blockIdx&7 (round-robin XCD), each shard
// scans all dst's but only counts its own range -> cnt lines stay XCD-local.
__global__ __launch_bounds__(256) void hist_k(const int* __restrict__ ei,
                                              int* __restrict__ cnt) {
  int shard = blockIdx.x & 7;
  int blk = blockIdx.x >> 3;
  int lo = shard * SHW, hi = lo + SHW;
  for (int e = blk * 256 + threadIdx.x; e < NE; e += NB_SHARD * 256) {
    int dst = ei[NE + e];
    if (dst >= lo && dst < hi) atomicAdd(&cnt[dst], 1);
  }
}

// hierarchical scan stage 1: per-block sums of cnt
__global__ __launch_bounds__(256) void blocksum_k(const int* __restrict__ cnt,
                                                  int* __restrict__ bsum) {
  __shared__ int red[4];
  int i = blockIdx.x * 256 + threadIdx.x;
  int v = (i < NN) ? cnt[i] : 0;
#pragma unroll
  for (int off = 32; off; off >>= 1) v += __shfl_down(v, off, 64);
  int wv = threadIdx.x >> 6;
  if ((threadIdx.x & 63) == 0) red[wv] = v;
  __syncthreads();
  if (threadIdx.x == 0) bsum[blockIdx.x] = red[0] + red[1] + red[2] + red[3];
}

// stage 2: exclusive scan of block sums (single tiny block)
__global__ __launch_bounds__(256) void scan_bsum_k(int* __restrict__ bsum) {
  __shared__ int s[256];
  int t = threadIdx.x;
  int v = (t < NBLK_SCAN) ? bsum[t] : 0;
  s[t] = v;
  __syncthreads();
#pragma unroll
  for (int off = 1; off < 256; off <<= 1) {
    int u = (t >= off) ? s[t - off] : 0;
    __syncthreads();
    s[t] += u;
    __syncthreads();
  }
  if (t < NBLK_SCAN) bsum[t] = s[t] - v;   // exclusive
}

// stage 3: in-block exclusive scan + block prefix -> rowptr, cursor
__global__ __launch_bounds__(256) void fill_k(const int* __restrict__ cnt,
    const int* __restrict__ bsum, int* __restrict__ rowptr,
    int* __restrict__ cursor) {
  __shared__ int s[256];
  int t = threadIdx.x;
  int i = blockIdx.x * 256 + t;
  int c = (i < NN) ? cnt[i] : 0;   // read before cursor write (aliased)
  s[t] = c;
  __syncthreads();
#pragma unroll
  for (int off = 1; off < 256; off <<= 1) {
    int u = (t >= off) ? s[t - off] : 0;
    __syncthreads();
    s[t] += u;
    __syncthreads();
  }
  int pre = bsum[blockIdx.x] + s[t] - c;
  if (i < NN) {
    rowptr[i] = pre;
    cursor[i] = pre;
  }
  if (i == NN - 1) rowptr[NN] = NE;
}

// XCD-sharded counting sort: srcs (ushort) lines written by one XCD only.
__global__ __launch_bounds__(256) void sort_k(const int* __restrict__ ei,
    int* __restrict__ cursor, unsigned short* __restrict__ srcs) {
  int shard = blockIdx.x & 7;
  int blk = blockIdx.x >> 3;
  int lo = shard * SHW, hi = lo + SHW;
  for (int e = blk * 256 + threadIdx.x; e < NE; e += NB_SHARD * 256) {
    int dst = ei[NE + e];
    if (dst >= lo && dst < hi) {
      int pos = atomicAdd(&cursor[dst], 1);
      srcs[pos] = (unsigned short)ei[e];
    }
  }
}

// gather bf16 x rows, mean, write bf16 agg into A-buffer agg-half (16 lanes/node)
__global__ __launch_bounds__(256) void gather_k(const int* __restrict__ rowptr,
    const unsigned short* __restrict__ srcs, unsigned short* Abuf) {
  int t = blockIdx.x * 256 + threadIdx.x;
  int n = t >> 4, q = t & 15;
  if (n >= NN) return;
  int b = rowptr[n], e = rowptr[n + 1];
  float a0=0,a1=0,a2=0,a3=0,a4=0,a5=0,a6=0,a7=0;
  int i = b;
  for (; i + 1 < e; i += 2) {
    int s0 = srcs[i], s1 = srcs[i + 1];
    uint4 v0 = *(const uint4*)(Abuf + (size_t)s0 * 256 + 128 + q * 8);
    uint4 v1 = *(const uint4*)(Abuf + (size_t)s1 * 256 + 128 + q * 8);
    a0 += bf_lo(v0.x) + bf_lo(v1.x);  a1 += bf_hi(v0.x) + bf_hi(v1.x);
    a2 += bf_lo(v0.y) + bf_lo(v1.y);  a3 += bf_hi(v0.y) + bf_hi(v1.y);
    a4 += bf_lo(v0.z) + bf_lo(v1.z);  a5 += bf_hi(v0.z) + bf_hi(v1.z);
    a6 += bf_lo(v0.w) + bf_lo(v1.w);  a7 += bf_hi(v0.w) + bf_hi(v1.w);
  }
  if (i < e) {
    int s0 = srcs[i];
    uint4 v0 = *(const uint4*)(Abuf + (size_t)s0 * 256 + 128 + q * 8);
    a0 += bf_lo(v0.x); a1 += bf_hi(v0.x);
    a2 += bf_lo(v0.y); a3 += bf_hi(v0.y);
    a4 += bf_lo(v0.z); a5 += bf_hi(v0.z);
    a6 += bf_lo(v0.w); a7 += bf_hi(v0.w);
  }
  float inv = 1.0f / fmaxf((float)(e - b), 1.0f);
  uint4 o;
  o.x = (unsigned)f2bf(a0 * inv) | ((unsigned)f2bf(a1 * inv) << 16);
  o.y = (unsigned)f2bf(a2 * inv) | ((unsigned)f2bf(a3 * inv) << 16);
  o.z = (unsigned)f2bf(a4 * inv) | ((unsigned)f2bf(a5 * inv) << 16);
  o.w = (unsigned)f2bf(a6 * inv) | ((unsigned)f2bf(a7 * inv) << 16);
  *(uint4*)(Abuf + (size_t)n * 256 + q * 8) = o;
}

// MFMA GEMM: out[n][c] = A[n][:] @ Wcat[:][c] + bl[c]; A bf16 [NN][256] aliases
// out f32 [NN][128] (same bytes); each wave reads only its own 16 rows.
__global__ __launch_bounds__(256) void gemm_k(const unsigned short* Abuf,
    const unsigned short* __restrict__ wp, const float* __restrict__ bl,
    float* out) {
  int wave = threadIdx.x >> 6;
  int lane = threadIdx.x & 63;
  int base = blockIdx.x * 64 + wave * 16;
  int row = lane & 15, kg = lane >> 4;
  int node = base + row;
  if (node > NN - 1) node = NN - 1;
  const unsigned short* arow = Abuf + (size_t)node * 256 + kg * 8;
  f32x4 acc[8] = {};
#pragma unroll
  for (int ks = 0; ks < 8; ++ks) {
    v8bf a = __builtin_bit_cast(v8bf, *(const uint4*)(arow + ks * 32));
    const unsigned short* wrow = wp + ks * 4096 + lane * 8;
#pragma unroll
    for (int nt = 0; nt < 8; ++nt) {
      v8bf b = __builtin_bit_cast(v8bf, *(const uint4*)(wrow + nt * 512));
      acc[nt] = __builtin_amdgcn_mfma_f32_16x16x32_bf16(a, b, acc[nt], 0, 0, 0);
    }
  }
  int c0 = lane & 15;
  float bv[8];
#pragma unroll
  for (int nt = 0; nt < 8; ++nt) bv[nt] = bl[nt * 16 + c0];
#pragma unroll
  for (int j = 0; j < 4; ++j) {
    int n = base + kg * 4 + j;
    if (n >= NN) break;
    float* orow = out + (size_t)n * HD;
#pragma unroll
    for (int nt = 0; nt < 8; ++nt) orow[nt * 16 + c0] = acc[nt][j] + bv[nt];
  }
}

// single pass: per-graph sum, sumsq of out + node counts (thread 0)
__global__ __launch_bounds__(128) void stats_k(const float* __restrict__ out,
    const int* __restrict__ batch, float* __restrict__ gsum,
    float* __restrict__ gsq, float* __restrict__ gcnt) {
  int d = threadIdx.x;
  int nstart = blockIdx.x * 64;
  if (nstart >= NN) return;
  int nend = min(nstart + 64, NN);
  int cur = batch[nstart];
  float s = 0.0f, ss = 0.0f;
  int run = 0;
  for (int n = nstart; n < nend; ++n) {
    int g = batch[n];
    if (g != cur) {
      atomicAdd(gsum + cur * HD + d, s);
      atomicAdd(gsq + cur * HD + d, ss);
      if (d == 0) atomicAdd(gcnt + cur, (float)run);
      s = 0.0f; ss = 0.0f; run = 0; cur = g;
    }
    float v = out[(size_t)n * HD + d];
    s += v; ss += v * v; run++;
  }
  atomicAdd(gsum + cur * HD + d, s);
  atomicAdd(gsq + cur * HD + d, ss);
  if (d == 0) atomicAdd(gcnt + cur, (float)run);
}

// fused: mean/rstd from raw sums (tiny hot region) + norm + GELU + residual
__global__ __launch_bounds__(256) void final_k(float* __restrict__ out,
    const float* __restrict__ x, const int* __restrict__ batch,
    const float* __restrict__ gsum, const float* __restrict__ gsq,
    const float* __restrict__ gcnt, const float* __restrict__ alpha,
    const float* __restrict__ gw, const float* __restrict__ gb) {
  size_t i = ((size_t)blockIdx.x * 256 + threadIdx.x) * 4;
  if (i >= (size_t)NN * HD) return;
  int n = (int)(i >> 7);
  int d = (int)(i & 127);
  int g = batch[n];
  float cinv = 1.0f / fmaxf(gcnt[g], 1.0f);
  float4 v  = *(float4*)(out + i);
  float4 xv = *(const float4*)(x + i);
  float4 al = *(const float4*)(alpha + d);
  float4 w  = *(const float4*)(gw + d);
  float4 b  = *(const float4*)(gb + d);
  float4 sm = *(const float4*)(gsum + (size_t)g * HD + d);
  float4 sq = *(const float4*)(gsq + (size_t)g * HD + d);
  float vv[4] = {v.x, v.y, v.z, v.w};
  float xx[4] = {xv.x, xv.y, xv.z, xv.w};
  float aa[4] = {al.x, al.y, al.z, al.w};
  float ww[4] = {w.x, w.y, w.z, w.w};
  float bb[4] = {b.x, b.y, b.z, b.w};
  float mm[4] = {sm.x, sm.y, sm.z, sm.w};
  float qq[4] = {sq.x, sq.y, sq.z, sq.w};
  float r[4];
#pragma unroll
  for (int c = 0; c < 4; ++c) {
    float mu = mm[c] * cinv;
    float a = aa[c];
    float var = qq[c] * cinv - mu * mu * (2.0f * a - a * a);
    float rs = rsqrtf(fmaxf(var, 0.0f) + GN_EPS);
    float sub = vv[c] - a * mu;
    float nm  = ww[c] * sub * rs + bb[c];
    float ge  = 0.5f * nm * (1.0f + erff(nm * 0.70710678118654752f));
    r[c] = ge + xx[c];
  }
  float4 res = {r[0], r[1], r[2], r[3]};
  *(float4*)(out + i) = res;
}

extern "C" void kernel_launch(void* const* d_in, const int* in_sizes, int n_in,
                              void* d_out, int out_size, void* d_ws, size_t ws_size,
                              hipStream_t stream) {
  const float* x     = (const float*)d_in[0];
  const int*   ei    = (const int*)d_in[1];
  const int*   batch = (const int*)d_in[2];
  const float* Wl    = (const float*)d_in[3];
  const float* bl    = (const float*)d_in[4];
  const float* Wr    = (const float*)d_in[5];
  const float* gw    = (const float*)d_in[6];
  const float* gb    = (const float*)d_in[7];
  const float* alpha = (const float*)d_in[8];

  float* out = (float*)d_out;
  unsigned short* Abuf = (unsigned short*)d_out;   // bf16 [NN][256] alias
  int*   wsi = (int*)d_ws;
  float* wsf = (float*)d_ws;
  int* rowptr = wsi + ROWPTR_OFF;
  int* cursor = wsi + CURSOR_OFF;
  float* gsum = wsf + GSUM_OFF;
  float* gsq  = wsf + GSQ_OFF;
  float* gcnt = wsf + GCNT_OFF;
  unsigned short* srcs = (unsigned short*)(wsi + SRCS_OFF);
  int* bsum   = wsi + BSUM_OFF;
  unsigned short* wpack = (unsigned short*)(wsi + WPACK_OFF);

  // zeroing is fused into prep_k (hipMemsetAsync graph node = 41us pathology)
  prep_k<<<3125, 256, 0, stream>>>(x, Wl, Wr, Abuf, wpack, cursor);

  hist_k<<<NSH * NB_SHARD, 256, 0, stream>>>(ei, cursor);
  blocksum_k<<<NBLK_SCAN, 256, 0, stream>>>(cursor, bsum);
  scan_bsum_k<<<1, 256, 0, stream>>>(bsum);
  fill_k<<<NBLK_SCAN, 256, 0, stream>>>(cursor, bsum, rowptr, cursor);
  sort_k<<<NSH * NB_SHARD, 256, 0, stream>>>(ei, cursor, srcs);

  gather_k<<<(NN * 16 + 255) / 256, 256, 0, stream>>>(rowptr, srcs, Abuf);

  gemm_k<<<(NN + 63) / 64, 256, 0, stream>>>(Abuf, wpack, bl, out);

  stats_k<<<(NN + 63) / 64, 128, 0, stream>>>(out, batch, gsum, gsq, gcnt);

  final_k<<<(NN * HD / 4 + 255) / 256, 256, 0, stream>>>(
      out, x, batch, gsum, gsq, gcnt, alpha, gw, gb);
}